// Round 15
// baseline (1169.538 us; speedup 1.0000x reference)
//
#include <hip/hip_runtime.h>
#include <hip/hip_bf16.h>

#define NIN    512
#define NEVAL  1536
#define NCOLS  2048
#define NOUT   256
#define OUT_BASE 1280
#define NBLK   48       // NEVAL / 32

typedef __attribute__((ext_vector_type(8))) short short8;   // 8 bf16 (4 VGPRs)
typedef __attribute__((ext_vector_type(4))) float floatx4;  // MFMA C/D

// ---------- helpers ----------

__device__ __forceinline__ unsigned short f2bf(float f) {
    __hip_bfloat16 h = __float2bfloat16(f);
    return __builtin_bit_cast(unsigned short, h);
}
__device__ __forceinline__ unsigned pack2(float a, float b) {
    return (unsigned)f2bf(a) | ((unsigned)f2bf(b) << 16);
}
// sigmoid(clip(5z,-60,60)): clamp dropped — v_exp overflow gives exact 0/1.
__device__ __forceinline__ float sigmoid5(float z) {
    return __builtin_amdgcn_rcpf(1.0f + __expf(-5.0f * z));
}

// ---------- W fp32 -> bf16 (d_ws re-poisoned every launch, so rerun) ----------

__global__ __launch_bounds__(256) void wconv(const float* __restrict__ W,
                                             ushort* __restrict__ Wb, int n8) {
    int i = blockIdx.x * blockDim.x + threadIdx.x;
    if (i < n8) {
        float4 v0 = ((const float4*)W)[2 * i];
        float4 v1 = ((const float4*)W)[2 * i + 1];
        uint4 pk;
        pk.x = pack2(v0.x, v0.y); pk.y = pack2(v0.z, v0.w);
        pk.z = pack2(v1.x, v1.y); pk.w = pack2(v1.z, v1.w);
        ((uint4*)Wb)[i] = pk;
    }
}

// ---------- main kernel ----------
// 256 WGs x 1024 threads (16 waves), 1 WG/CU. WG owns 16 rows.
// ROUND-15 = ROUND-13/14 structure (single-wave chain: wave 0, lane r =
// row r, per-lane z for all 32 nodes in 8 named float4s; sigmoid on own
// register — no cross-lane on the serial path; rank-1 updates from
// uniform-address ds_read broadcasts) with the spill ACTUALLY fixed:
//   amdgpu_waves_per_eu(4,4): pins min AND max waves/EU to 4 -> VGPR
//   budget 512/4 = 128. R14's __launch_bounds__(1024,4) only set the MIN
//   (a floor); the allocator still targeted 8 waves/EU -> 64 VGPRs ->
//   Z spilled to scratch (533 MB/dispatch HBM writes, the 1100us).
//   4 waves/EU is already the LDS-imposed ceiling (87 KB -> 1 WG/CU),
//   so capping costs nothing.
// Per 32-node block k (cols [L0, L0+32), L0 = 512+32k):
//   A: barrier — chain(k-1) O/Wt/Zfin-reads done
//   all: Wt stage (Wt[col*36+node]), main(k+1) MFMAs, tail MFMA
//        (owner ksp==(k+7)&7), Zred write
//   B: barrier — Zred visible
//   all: gather 8 partials + bias -> Zfin[node*17+row]
//   C: barrier — Zfin visible
//   wave0: chain (32 steps); writes o -> O (bf16) + out (global)

__global__ __launch_bounds__(1024)
__attribute__((amdgpu_waves_per_eu(4, 4)))
void ffnet(const float* __restrict__ x,
           const float* __restrict__ W,
           const ushort* __restrict__ Wb,
           const float* __restrict__ bias,
           float* __restrict__ out) {
    __shared__ unsigned short O[16 * 2048];   // 64 KB
    __shared__ float Zred[16 * 256];          // 16 KB [wave][lane][reg]
    __shared__ float Wt[32 * 36];             // 4.6 KB diag, Wt[col*36+node]
    __shared__ float Zfin[32 * 17];           // 2.2 KB z-init, [node*17+row]

    const int t    = threadIdx.x;
    const int w    = t >> 6;        // wave 0..15
    const int lane = t & 63;

    // phase-A role: 2 node-halves x 8 K-split slots
    const int m16  = lane & 15;     // A row (batch row) / D col (node)
    const int quad = lane >> 4;     // 0..3
    const int half = w >> 3;        // 0..1
    const int ksp  = w & 7;         // 0..7
    const int arow = m16 << 11;
    const int arot = m16 << 3;

    const int ii   = lane & 31;     // node within block (gather role)
    const long row = (long)blockIdx.x * 16 + w;
    const int rot  = w << 3;

    // chain role (wave 0): lane r16 = batch row (lanes 16-63 mirror)
    const int r16  = lane & 15;
    const long ob  = ((long)blockIdx.x * 16 + r16) * NOUT - OUT_BASE;

    // Wt staging role: one float per thread
    const int sn = t >> 5;          // 0..31 node i
    const int sc = t & 31;          // 0..31 col j

    // ---- stage x row w into LDS as bf16 (swizzled) ----
    {
        const float* xr = x + row * NIN + lane * 8;
        float4 v0 = *(const float4*)xr;
        float4 v1 = *(const float4*)(xr + 4);
        uint4 pk;
        pk.x = pack2(v0.x, v0.y); pk.y = pack2(v0.z, v0.w);
        pk.z = pack2(v1.x, v1.y); pk.w = pack2(v1.z, v1.w);
        *(uint4*)&O[(w << 11) + ((lane * 8 + rot) & 2047)] = pk;
    }
    __syncthreads();

    // ---- prologue: main(0) over columns [0, 480) ----
    floatx4 acc = {0.f, 0.f, 0.f, 0.f};
    {
        const ushort* wb = Wb + (size_t)(half * 16 + m16) * NCOLS;
        for (int kk = ksp * 32; kk < NIN - 32; kk += 256) {
            short8 a = *(const short8*)&O[arow + ((kk + quad * 8 + arot) & 2047)];
            short8 b = *(const short8*)&wb[kk + quad * 8];
            acc = __builtin_amdgcn_mfma_f32_16x16x32_bf16(a, b, acc, 0, 0, 0);
        }
    }

    for (int k = 0; k < NBLK; ++k) {
        const int i0 = k << 5;
        const int L0 = NIN + i0;
        const int g  = i0 + ii;

        __syncthreads();            // barrier A

        // Wt diag load (1 float/thread) + bias, issued early
        float wtv = W[(size_t)(i0 + sn) * NCOLS + L0 + sc];
        float bi  = bias[g];

        // main(k+1) over [0, L0) — drains overlap Wt stage / barrier B
        floatx4 accN = {0.f, 0.f, 0.f, 0.f};
        if (k + 1 < NBLK) {
            const ushort* wb = Wb + (size_t)(i0 + 32 + half * 16 + m16) * NCOLS;
            #pragma unroll 2
            for (int kk = ksp * 32; kk < L0; kk += 256) {
                short8 a = *(const short8*)&O[arow + ((kk + quad * 8 + arot) & 2047)];
                short8 b = *(const short8*)&wb[kk + quad * 8];
                accN = __builtin_amdgcn_mfma_f32_16x16x32_bf16(a, b, accN, 0, 0, 0);
            }
        }

        // stage diag weights: Wt[col*36 + node]
        Wt[sc * 36 + sn] = wtv;

        // tail: K=32 MFMA over [L0-32, L0) — chunk 15+k, owner ksp=(k+7)&7
        if (ksp == ((k + 7) & 7)) {
            const ushort* wb = Wb + (size_t)(i0 + half * 16 + m16) * NCOLS;
            const int ts = L0 - 32;
            short8 a = *(const short8*)&O[arow + ((ts + quad * 8 + arot) & 2047)];
            short8 b = *(const short8*)&wb[ts + quad * 8];
            acc = __builtin_amdgcn_mfma_f32_16x16x32_bf16(a, b, acc, 0, 0, 0);
        }

        // D frag: lane q*16+n holds Z[m=4q+reg][n]
        *(floatx4*)&Zred[(w << 8) + (lane << 2)] = acc;
        __syncthreads();            // barrier B

        // gather z-init for (row w, node ii) -> Zfin[ii*17 + w]
        {
            const int h = ii >> 4, n = ii & 15;
            const int ridx = ((w >> 2) << 6) + (n << 2) + (w & 3);
            float zacc = bi;
            #pragma unroll
            for (int p = 0; p < 8; ++p)
                zacc += Zred[(((h << 3) + p) << 8) + ridx];
            if (lane < 32)
                Zfin[ii * 17 + w] = zacc;
        }
        __syncthreads();            // barrier C: Zfin visible

        // ---- chain: wave 0 only, z in 8 named float4 registers ----
        if (w == 0) {
            float4 Z0, Z1, Z2, Z3, Z4, Z5, Z6, Z7;
            #define LDZ(G)                                                     \
                Z##G.x = Zfin[((G) * 4 + 0) * 17 + r16];                       \
                Z##G.y = Zfin[((G) * 4 + 1) * 17 + r16];                       \
                Z##G.z = Zfin[((G) * 4 + 2) * 17 + r16];                       \
                Z##G.w = Zfin[((G) * 4 + 3) * 17 + r16];
            LDZ(0) LDZ(1) LDZ(2) LDZ(3) LDZ(4) LDZ(5) LDZ(6) LDZ(7)
            #undef LDZ

            #define UP(G, J)                                                   \
                {                                                              \
                    float4 wq = *(const float4*)&Wt[(J) * 36 + (G) * 4];       \
                    Z##G.x = fmaf(wq.x, o, Z##G.x);                            \
                    Z##G.y = fmaf(wq.y, o, Z##G.y);                            \
                    Z##G.z = fmaf(wq.z, o, Z##G.z);                            \
                    Z##G.w = fmaf(wq.w, o, Z##G.w);                            \
                }
            #define SG(J, ZC)                                                  \
                float o = sigmoid5(ZC);                                        \
                if (lane < 16) {                                               \
                    O[(r16 << 11) + ((L0 + (J) + (r16 << 3)) & 2047)] =        \
                        f2bf(o);                                               \
                    if (i0 + (J) >= OUT_BASE) out[ob + i0 + (J)] = o;          \
                }
            // update groups start at (J+1)>>2 (Wt is strictly lower-tri)
            { SG( 0, Z0.x) UP(0, 0) UP(1, 0) UP(2, 0) UP(3, 0) UP(4, 0) UP(5, 0) UP(6, 0) UP(7, 0) }
            { SG( 1, Z0.y) UP(0, 1) UP(1, 1) UP(2, 1) UP(3, 1) UP(4, 1) UP(5, 1) UP(6, 1) UP(7, 1) }
            { SG( 2, Z0.z) UP(0, 2) UP(1, 2) UP(2, 2) UP(3, 2) UP(4, 2) UP(5, 2) UP(6, 2) UP(7, 2) }
            { SG( 3, Z0.w) UP(1, 3) UP(2, 3) UP(3, 3) UP(4, 3) UP(5, 3) UP(6, 3) UP(7, 3) }
            { SG( 4, Z1.x) UP(1, 4) UP(2, 4) UP(3, 4) UP(4, 4) UP(5, 4) UP(6, 4) UP(7, 4) }
            { SG( 5, Z1.y) UP(1, 5) UP(2, 5) UP(3, 5) UP(4, 5) UP(5, 5) UP(6, 5) UP(7, 5) }
            { SG( 6, Z1.z) UP(1, 6) UP(2, 6) UP(3, 6) UP(4, 6) UP(5, 6) UP(6, 6) UP(7, 6) }
            { SG( 7, Z1.w) UP(2, 7) UP(3, 7) UP(4, 7) UP(5, 7) UP(6, 7) UP(7, 7) }
            { SG( 8, Z2.x) UP(2, 8) UP(3, 8) UP(4, 8) UP(5, 8) UP(6, 8) UP(7, 8) }
            { SG( 9, Z2.y) UP(2, 9) UP(3, 9) UP(4, 9) UP(5, 9) UP(6, 9) UP(7, 9) }
            { SG(10, Z2.z) UP(2,10) UP(3,10) UP(4,10) UP(5,10) UP(6,10) UP(7,10) }
            { SG(11, Z2.w) UP(3,11) UP(4,11) UP(5,11) UP(6,11) UP(7,11) }
            { SG(12, Z3.x) UP(3,12) UP(4,12) UP(5,12) UP(6,12) UP(7,12) }
            { SG(13, Z3.y) UP(3,13) UP(4,13) UP(5,13) UP(6,13) UP(7,13) }
            { SG(14, Z3.z) UP(3,14) UP(4,14) UP(5,14) UP(6,14) UP(7,14) }
            { SG(15, Z3.w) UP(4,15) UP(5,15) UP(6,15) UP(7,15) }
            { SG(16, Z4.x) UP(4,16) UP(5,16) UP(6,16) UP(7,16) }
            { SG(17, Z4.y) UP(4,17) UP(5,17) UP(6,17) UP(7,17) }
            { SG(18, Z4.z) UP(4,18) UP(5,18) UP(6,18) UP(7,18) }
            { SG(19, Z4.w) UP(5,19) UP(6,19) UP(7,19) }
            { SG(20, Z5.x) UP(5,20) UP(6,20) UP(7,20) }
            { SG(21, Z5.y) UP(5,21) UP(6,21) UP(7,21) }
            { SG(22, Z5.z) UP(5,22) UP(6,22) UP(7,22) }
            { SG(23, Z5.w) UP(6,23) UP(7,23) }
            { SG(24, Z6.x) UP(6,24) UP(7,24) }
            { SG(25, Z6.y) UP(6,25) UP(7,25) }
            { SG(26, Z6.z) UP(6,26) UP(7,26) }
            { SG(27, Z6.w) UP(7,27) }
            { SG(28, Z7.x) UP(7,28) }
            { SG(29, Z7.y) UP(7,29) }
            { SG(30, Z7.z) UP(7,30) }
            { SG(31, Z7.w) }
            #undef SG
            #undef UP
        }
        acc = accN;
    }
}

// ---------- launch ----------

extern "C" void kernel_launch(void* const* d_in, const int* in_sizes, int n_in,
                              void* d_out, int out_size, void* d_ws, size_t ws_size,
                              hipStream_t stream) {
    const float* x  = (const float*)d_in[0];   // [4096, 512]
    const float* W  = (const float*)d_in[1];   // [1536, 2048]
    const float* b  = (const float*)d_in[2];   // [1536]
    float* out = (float*)d_out;                // [4096, 256]
    ushort* Wb = (ushort*)d_ws;                // bf16 W copy (6.3 MB)

    int n8 = NEVAL * NCOLS / 8;
    wconv<<<n8 / 256, 256, 0, stream>>>(W, Wb, n8);
    ffnet<<<4096 / 16, 1024, 0, stream>>>(x, W, Wb, b, out);
}

// Round 16
// 352.610 us; speedup vs baseline: 3.3168x; 3.3168x over previous
//
#include <hip/hip_runtime.h>
#include <hip/hip_bf16.h>

#define NIN    512
#define NEVAL  1536
#define NCOLS  2048
#define NOUT   256
#define OUT_BASE 1280
#define NBLK   48       // NEVAL / 32

typedef __attribute__((ext_vector_type(8))) short short8;   // 8 bf16 (4 VGPRs)
typedef __attribute__((ext_vector_type(4))) float floatx4;  // MFMA C/D

// ---------- helpers ----------

__device__ __forceinline__ unsigned short f2bf(float f) {
    __hip_bfloat16 h = __float2bfloat16(f);
    return __builtin_bit_cast(unsigned short, h);
}
__device__ __forceinline__ unsigned pack2(float a, float b) {
    return (unsigned)f2bf(a) | ((unsigned)f2bf(b) << 16);
}
// sigmoid(clip(5z,-60,60)): clamp dropped — v_exp overflow gives exact 0/1.
__device__ __forceinline__ float sigmoid5(float z) {
    return __builtin_amdgcn_rcpf(1.0f + __expf(-5.0f * z));
}

// ---------- W fp32 -> bf16 (d_ws re-poisoned every launch, so rerun) ----------

__global__ __launch_bounds__(256) void wconv(const float* __restrict__ W,
                                             ushort* __restrict__ Wb, int n8) {
    int i = blockIdx.x * blockDim.x + threadIdx.x;
    if (i < n8) {
        float4 v0 = ((const float4*)W)[2 * i];
        float4 v1 = ((const float4*)W)[2 * i + 1];
        uint4 pk;
        pk.x = pack2(v0.x, v0.y); pk.y = pack2(v0.z, v0.w);
        pk.z = pack2(v1.x, v1.y); pk.w = pack2(v1.z, v1.w);
        ((uint4*)Wb)[i] = pk;
    }
}

// ---------- main kernel ----------
// 256 WGs x 1024 threads (16 waves), 1 WG/CU. WG owns 16 rows.
// ROUND-16: single-wave chain with per-lane state SIZED TO THE 64-VGPR
// BUDGET. R13-R15 proved the allocator will not hold 32 computed floats per
// lane (spilled to scratch, 533 MB/dispatch, ~1100us) under any of: named
// float4s, __launch_bounds__ min-waves, amdgpu_waves_per_eu(4,4). Fix: split
// the 32 z across 4 lane-groups — chain lane = r*4+gq (r=row 0..15,
// gq=group 0..3), each lane holds 8 z as named scalars (~30 VGPRs).
// Step j (G=j>>3, JM=j&7 literals): owner group sigmoids z_JM; __shfl
// broadcast within the 4-lane cluster (same 32-lane half); all groups
// update their 8 z from Wt[j*36+gq*8..] (b128, group-broadcast,
// conflict-free; Wt=0 for i<=j covers the triangle mask). Sigmoid issue
// per node: ONE wave-op for all 16 rows (R12 paid 16 wave-ops).
// Per 32-node block k (cols [L0, L0+32), L0 = 512+32k):
//   A: barrier — chain(k-1) O/Wt/Zfin-reads done
//   all: Wt stage (Wt[col*36+node]), main(k+1) MFMAs, tail MFMA
//        (owner ksp==(k+7)&7), Zred write
//   B: barrier — Zred visible
//   all: gather 8 partials + bias -> Zfin[row*36+node]
//   C: barrier — Zfin visible
//   wave0: chain (32 steps); writes o -> O (bf16) + out (global)

__global__ __launch_bounds__(1024)
void ffnet(const float* __restrict__ x,
           const float* __restrict__ W,
           const ushort* __restrict__ Wb,
           const float* __restrict__ bias,
           float* __restrict__ out) {
    __shared__ unsigned short O[16 * 2048];   // 64 KB
    __shared__ float Zred[16 * 256];          // 16 KB [wave][lane][reg]
    __shared__ float Wt[32 * 36];             // 4.6 KB diag, Wt[col*36+node]
    __shared__ float Zfin[16 * 36];           // 2.3 KB z-init, [row*36+node]

    const int t    = threadIdx.x;
    const int w    = t >> 6;        // wave 0..15
    const int lane = t & 63;

    // phase-A role: 2 node-halves x 8 K-split slots
    const int m16  = lane & 15;     // A row (batch row) / D col (node)
    const int quad = lane >> 4;     // 0..3
    const int half = w >> 3;        // 0..1
    const int ksp  = w & 7;         // 0..7
    const int arow = m16 << 11;
    const int arot = m16 << 3;

    const int ii   = lane & 31;     // node within block (gather role)
    const long row = (long)blockIdx.x * 16 + w;
    const int rot  = w << 3;

    // Wt staging role: one float per thread
    const int sn = t >> 5;          // 0..31 node i
    const int sc = t & 31;          // 0..31 col j

    // ---- stage x row w into LDS as bf16 (swizzled) ----
    {
        const float* xr = x + row * NIN + lane * 8;
        float4 v0 = *(const float4*)xr;
        float4 v1 = *(const float4*)(xr + 4);
        uint4 pk;
        pk.x = pack2(v0.x, v0.y); pk.y = pack2(v0.z, v0.w);
        pk.z = pack2(v1.x, v1.y); pk.w = pack2(v1.z, v1.w);
        *(uint4*)&O[(w << 11) + ((lane * 8 + rot) & 2047)] = pk;
    }
    __syncthreads();

    // ---- prologue: main(0) over columns [0, 480) ----
    floatx4 acc = {0.f, 0.f, 0.f, 0.f};
    {
        const ushort* wb = Wb + (size_t)(half * 16 + m16) * NCOLS;
        for (int kk = ksp * 32; kk < NIN - 32; kk += 256) {
            short8 a = *(const short8*)&O[arow + ((kk + quad * 8 + arot) & 2047)];
            short8 b = *(const short8*)&wb[kk + quad * 8];
            acc = __builtin_amdgcn_mfma_f32_16x16x32_bf16(a, b, acc, 0, 0, 0);
        }
    }

    for (int k = 0; k < NBLK; ++k) {
        const int i0 = k << 5;
        const int L0 = NIN + i0;
        const int g  = i0 + ii;

        __syncthreads();            // barrier A

        // Wt diag load (1 float/thread) + bias, issued early
        float wtv = W[(size_t)(i0 + sn) * NCOLS + L0 + sc];
        float bi  = bias[g];

        // main(k+1) over [0, L0) — drains overlap Wt stage / barrier B
        floatx4 accN = {0.f, 0.f, 0.f, 0.f};
        if (k + 1 < NBLK) {
            const ushort* wb = Wb + (size_t)(i0 + 32 + half * 16 + m16) * NCOLS;
            #pragma unroll 2
            for (int kk = ksp * 32; kk < L0; kk += 256) {
                short8 a = *(const short8*)&O[arow + ((kk + quad * 8 + arot) & 2047)];
                short8 b = *(const short8*)&wb[kk + quad * 8];
                accN = __builtin_amdgcn_mfma_f32_16x16x32_bf16(a, b, accN, 0, 0, 0);
            }
        }

        // stage diag weights: Wt[col*36 + node]
        Wt[sc * 36 + sn] = wtv;

        // tail: K=32 MFMA over [L0-32, L0) — chunk 15+k, owner ksp=(k+7)&7
        if (ksp == ((k + 7) & 7)) {
            const ushort* wb = Wb + (size_t)(i0 + half * 16 + m16) * NCOLS;
            const int ts = L0 - 32;
            short8 a = *(const short8*)&O[arow + ((ts + quad * 8 + arot) & 2047)];
            short8 b = *(const short8*)&wb[ts + quad * 8];
            acc = __builtin_amdgcn_mfma_f32_16x16x32_bf16(a, b, acc, 0, 0, 0);
        }

        // D frag: lane q*16+n holds Z[m=4q+reg][n]
        *(floatx4*)&Zred[(w << 8) + (lane << 2)] = acc;
        __syncthreads();            // barrier B

        // gather z-init for (row w, node ii) -> Zfin[w*36 + ii]
        {
            const int h = ii >> 4, n = ii & 15;
            const int ridx = ((w >> 2) << 6) + (n << 2) + (w & 3);
            float zacc = bi;
            #pragma unroll
            for (int p = 0; p < 8; ++p)
                zacc += Zred[(((h << 3) + p) << 8) + ridx];
            if (lane < 32)
                Zfin[w * 36 + ii] = zacc;
        }
        __syncthreads();            // barrier C: Zfin + Wt visible

        // ---- chain: wave 0 only; lane = r*4+gq; 8 z per lane ----
        if (w == 0) {
            const int r   = lane >> 2;       // row 0..15
            const int gq  = lane & 3;        // z-group 0..3
            const int zb  = r * 36 + (gq << 3);
            const int wtb = gq << 3;
            float4 f0 = *(const float4*)&Zfin[zb];
            float4 f1 = *(const float4*)&Zfin[zb + 4];
            float z0 = f0.x, z1 = f0.y, z2 = f0.z, z3 = f0.w;
            float z4 = f1.x, z5 = f1.y, z6 = f1.z, z7 = f1.w;
            const long ob  = ((long)blockIdx.x * 16 + r) * NOUT - OUT_BASE;
            const int obase = r << 11;
            const int orot  = r << 3;

            #define CH(J, G, JM)                                               \
            {                                                                  \
                float oc = sigmoid5(z##JM);       /* valid on gq==G */         \
                float o  = __shfl(oc, (lane & 60) | (G), 64);                  \
                if (gq == (G)) {                                               \
                    O[obase + ((L0 + (J) + orot) & 2047)] = f2bf(oc);          \
                    if (i0 + (J) >= OUT_BASE) out[ob + i0 + (J)] = oc;         \
                }                                                              \
                float4 wq0 = *(const float4*)&Wt[(J) * 36 + wtb];              \
                float4 wq1 = *(const float4*)&Wt[(J) * 36 + wtb + 4];          \
                z0 = fmaf(wq0.x, o, z0); z1 = fmaf(wq0.y, o, z1);              \
                z2 = fmaf(wq0.z, o, z2); z3 = fmaf(wq0.w, o, z3);              \
                z4 = fmaf(wq1.x, o, z4); z5 = fmaf(wq1.y, o, z5);              \
                z6 = fmaf(wq1.z, o, z6); z7 = fmaf(wq1.w, o, z7);              \
            }
            CH( 0,0,0) CH( 1,0,1) CH( 2,0,2) CH( 3,0,3)
            CH( 4,0,4) CH( 5,0,5) CH( 6,0,6) CH( 7,0,7)
            CH( 8,1,0) CH( 9,1,1) CH(10,1,2) CH(11,1,3)
            CH(12,1,4) CH(13,1,5) CH(14,1,6) CH(15,1,7)
            CH(16,2,0) CH(17,2,1) CH(18,2,2) CH(19,2,3)
            CH(20,2,4) CH(21,2,5) CH(22,2,6) CH(23,2,7)
            CH(24,3,0) CH(25,3,1) CH(26,3,2) CH(27,3,3)
            CH(28,3,4) CH(29,3,5) CH(30,3,6) CH(31,3,7)
            #undef CH
        }
        acc = accN;
    }
}

// ---------- launch ----------

extern "C" void kernel_launch(void* const* d_in, const int* in_sizes, int n_in,
                              void* d_out, int out_size, void* d_ws, size_t ws_size,
                              hipStream_t stream) {
    const float* x  = (const float*)d_in[0];   // [4096, 512]
    const float* W  = (const float*)d_in[1];   // [1536, 2048]
    const float* b  = (const float*)d_in[2];   // [1536]
    float* out = (float*)d_out;                // [4096, 256]
    ushort* Wb = (ushort*)d_ws;                // bf16 W copy (6.3 MB)

    int n8 = NEVAL * NCOLS / 8;
    wconv<<<n8 / 256, 256, 0, stream>>>(W, Wb, n8);
    ffnet<<<4096 / 16, 1024, 0, stream>>>(x, W, Wb, b, out);
}